// Round 11
// baseline (80.071 us; speedup 1.0000x reference)
//
#include <hip/hip_runtime.h>

#define NCH 24
#define KS 11
#define TH 32          // output rows per tile
#define TW 64          // output cols per tile
#define IWC 76         // LDS col stride (>= TW+10+2, mult of 4)

typedef float vbuf_t[TH][IWC];   // one field: 32 x 76

// ===== vertical pass (rest kernel): rotating 10-deep register prefetch ====
// fields: 0 = x, 1 = y, 2 = xx+yy, 3 = xy
template<bool GUARD>
__device__ __forceinline__ void v_pass(
    const float* __restrict__ Xp, const float* __restrict__ Yp,
    const float* __restrict__ k, int H, int W, int gx0, int gy0, int tid,
    vbuf_t* vbuf)
{
    if (tid < 3 * IWC) {
        const int c  = tid % IWC;
        const int rg = tid / IWC;
        const int r0 = rg * 11;
        const int gc = gx0 + c;
        const bool cok = (!GUARD) || (gc < W);

        float acc[11][4];
#pragma unroll
        for (int i = 0; i < 11; ++i)
#pragma unroll
            for (int f = 0; f < 4; ++f) acc[i][f] = 0.f;

        const float* xptr = Xp + (size_t)(gy0 + r0) * W + gc;
        const float* yptr = Yp + (size_t)(gy0 + r0) * W + gc;

        float xr[10], yr[10];
#pragma unroll
        for (int i = 0; i < 10; ++i) {
            if (GUARD) {
                const int gy = gy0 + r0 + i;
                xr[i] = 0.f; yr[i] = 0.f;
                if (cok && gy < H) { xr[i] = xptr[0]; yr[i] = yptr[0]; }
            } else {
                xr[i] = xptr[0]; yr[i] = yptr[0];
            }
            xptr += W; yptr += W;
        }

#pragma unroll
        for (int ri = 0; ri < 21; ++ri) {
            const int s = ri % 10;
            const float xv = xr[s], yv = yr[s];
            if (ri + 10 < 21) {
                if (GUARD) {
                    const int gy = gy0 + r0 + ri + 10;
                    xr[s] = 0.f; yr[s] = 0.f;
                    if (cok && gy < H) { xr[s] = xptr[0]; yr[s] = yptr[0]; }
                } else {
                    xr[s] = xptr[0]; yr[s] = yptr[0];
                }
                xptr += W; yptr += W;
            }

            const float sq = fmaf(yv, yv, xv * xv);
            const float xy = xv * yv;
#pragma unroll
            for (int rv = 0; rv < 11; ++rv) {
                if (rv < (ri > 10 ? ri - 10 : 0)) continue;
                if (rv > (ri < 10 ? ri : 10)) continue;
                const float kt = k[ri - rv];
                acc[rv][0] += kt * xv;
                acc[rv][1] += kt * yv;
                acc[rv][2] += kt * sq;
                acc[rv][3] += kt * xy;
            }
        }
#pragma unroll
        for (int rv = 0; rv < 11; ++rv) {
            const int r = r0 + rv;
            if (r < TH) {
#pragma unroll
                for (int f = 0; f < 4; ++f)
                    vbuf[f][r][c] = acc[rv][f];
            }
        }
    }
}

// ===== scale-0 v-pass WITH in-register pooling (no input re-read) =========
// rg0 owns pooled rows 0-9 (input rows 0..19); rg1 rows 10-15 (rows 20..31).
// Col pairs via shfl_down(1); lvl2 col pairs via shfl_down(2) (lane%4==0
// readers never cross the wave boundary).
template<bool GUARD>
__device__ __forceinline__ void v_pass_pool(
    const float* __restrict__ Xp, const float* __restrict__ Yp,
    const float* __restrict__ k, int gx0, int gy0, int tid,
    vbuf_t* vbuf, float (*pl2)[8][16],
    float* __restrict__ X1, float* __restrict__ Y1,
    float* __restrict__ X2, float* __restrict__ Y2, int nc)
{
    const int W = 512, H = 512;
    if (tid < 3 * IWC) {
        const int c  = tid % IWC;
        const int rg = tid / IWC;
        const int r0 = rg * 11;
        const int gc = gx0 + c;
        const bool cok = (!GUARD) || (gc < W);

        float acc[11][4];
#pragma unroll
        for (int i = 0; i < 11; ++i)
#pragma unroll
            for (int f = 0; f < 4; ++f) acc[i][f] = 0.f;
        float px[10], py[10];
#pragma unroll
        for (int i = 0; i < 10; ++i) { px[i] = 0.f; py[i] = 0.f; }

        const float* xptr = Xp + (size_t)(gy0 + r0) * W + gc;
        const float* yptr = Yp + (size_t)(gy0 + r0) * W + gc;

#pragma unroll
        for (int ri = 0; ri < 21; ++ri) {
            float xv, yv;
            if (GUARD) {
                const int gy = gy0 + r0 + ri;
                xv = 0.f; yv = 0.f;
                if (cok && gy < H) { xv = xptr[0]; yv = yptr[0]; }
            } else {
                xv = xptr[0]; yv = yptr[0];
            }
            xptr += W; yptr += W;

            // pooling row-pair accumulation (static indices)
            if (rg == 0) {
                if (ri < 20) { px[ri >> 1] += xv; py[ri >> 1] += yv; }
            } else if (rg == 1) {
                if (ri >= 9) { px[(ri - 9) >> 1] += xv; py[(ri - 9) >> 1] += yv; }
            }

            const float sq = fmaf(yv, yv, xv * xv);
            const float xy = xv * yv;
#pragma unroll
            for (int rv = 0; rv < 11; ++rv) {
                if (rv < (ri > 10 ? ri - 10 : 0)) continue;
                if (rv > (ri < 10 ? ri : 10)) continue;
                const float kt = k[ri - rv];
                acc[rv][0] += kt * xv;
                acc[rv][1] += kt * yv;
                acc[rv][2] += kt * sq;
                acc[rv][3] += kt * xy;
            }
        }
#pragma unroll
        for (int rv = 0; rv < 11; ++rv) {
            const int r = r0 + rv;
            if (r < TH) {
#pragma unroll
                for (int f = 0; f < 4; ++f)
                    vbuf[f][r][c] = acc[rv][f];
            }
        }

        // pooled level 1 (16x32): col combine, even-c writes
        const int W2 = 256, W4 = 128;
#pragma unroll
        for (int j = 0; j < 10; ++j) {
            float sx = px[j] + __shfl_down(px[j], 1);
            float sy = py[j] + __shfl_down(py[j], 1);
            px[j] = sx; py[j] = sy;     // keep 2x2 sums for lvl2
            if (((c & 1) == 0) && (c < 64) && (rg == 0 || (rg == 1 && j < 6))) {
                int pr = (rg == 0) ? j : 10 + j;
                size_t d1 = (size_t)nc * W2 * W2 + (size_t)((gy0 >> 1) + pr) * W2 + ((gx0 >> 1) + (c >> 1));
                X1[d1] = 0.25f * sx;
                Y1[d1] = 0.25f * sy;
            }
        }
        // pooled level 2 (8x16): in-thread row pairs + shfl_down(2)
#pragma unroll
        for (int q = 0; q < 5; ++q) {
            float s2x = px[2 * q] + px[2 * q + 1];
            float s2y = py[2 * q] + py[2 * q + 1];
            s2x += __shfl_down(s2x, 2);
            s2y += __shfl_down(s2y, 2);
            if (((c & 3) == 0) && (c < 64) && (rg == 0 ? (q < 5) : (rg == 1 && q < 3))) {
                int r2 = (rg == 0) ? q : 5 + q;
                int c2 = c >> 2;
                float vx = s2x * 0.0625f, vy = s2y * 0.0625f;
                pl2[0][r2][c2] = vx;  pl2[1][r2][c2] = vy;
                size_t d2 = (size_t)nc * W4 * W4 + (size_t)((gy0 >> 2) + r2) * W4 + ((gx0 >> 2) + c2);
                X2[d2] = vx;  Y2[d2] = vy;
            }
        }
    }
}

// ===== horizontal pass: b128 LDS reads + SSIM (call after barrier) ========
template<bool GUARD>
__device__ __forceinline__ void h_pass(
    const float* __restrict__ k, int H, int W, int gx0, int gy0, int tid,
    vbuf_t* vbuf, float& ss_acc, float& cs_acc)
{
    const float c1 = 1e-4f, c2 = 9e-4f;
    const int row = tid >> 3;
    const int cg  = tid & 7;
    const int c0  = cg * 8;
    const bool rowok = (!GUARD) || ((gy0 + row) <= (H - KS));

    float hacc[4][8];
#pragma unroll
    for (int f = 0; f < 4; ++f)
#pragma unroll
        for (int j = 0; j < 8; ++j) hacc[f][j] = 0.f;

#pragma unroll
    for (int f = 0; f < 4; ++f) {
        const float4* vp = reinterpret_cast<const float4*>(&vbuf[f][row][c0]);
        float4 q0 = vp[0], q1 = vp[1], q2 = vp[2], q3 = vp[3], q4 = vp[4];
        float v[20] = {q0.x,q0.y,q0.z,q0.w, q1.x,q1.y,q1.z,q1.w,
                       q2.x,q2.y,q2.z,q2.w, q3.x,q3.y,q3.z,q3.w,
                       q4.x,q4.y,q4.z,q4.w};
#pragma unroll
        for (int j = 0; j < 8; ++j)
#pragma unroll
            for (int t = 0; t < KS; ++t)
                hacc[f][j] += k[t] * v[j + t];
    }

#pragma unroll
    for (int j = 0; j < 8; ++j) {
        bool ok = rowok && ((!GUARD) || ((gx0 + c0 + j) <= (W - KS)));
        if (ok) {
            float mx = hacc[0][j], my = hacc[1][j];
            float S = hacc[2][j], vxy = hacc[3][j];
            float mxx = mx * mx, myy = my * my, mxy = mx * my;
            float msum = mxx + myy;
            float sxy = vxy - mxy, ssum = S - msum;
            float cs = (2.f * sxy + c2) * __builtin_amdgcn_rcpf(ssum + c2);
            float ssv = (2.f * mxy + c1) * __builtin_amdgcn_rcpf(msum + c1) * cs;
            ss_acc += ssv; cs_acc += cs;
        }
    }
}

__device__ __forceinline__ void block_reduce_store(
    float ss_acc, float cs_acc, int tid, float* red, float* slot)
{
    for (int off = 32; off > 0; off >>= 1) {
        ss_acc += __shfl_down(ss_acc, off);
        cs_acc += __shfl_down(cs_acc, off);
    }
    const int wave = tid >> 6;
    if ((tid & 63) == 0) { red[wave * 2] = ss_acc; red[wave * 2 + 1] = cs_acc; }
    __syncthreads();
    if (tid == 0) {
        slot[0] = red[0] + red[2] + red[4] + red[6];
        slot[1] = red[1] + red[3] + red[5] + red[7];
    }
}

// ================= scale-0: SSIM + in-register pooled pyramid =============
// LDS = 38912 + 1024 + 256 + 32 = 40224 <= 40960 -> HW can run 4 blocks/CU.
// LB(256,3) NOT (256,4): the latter caps VGPR at 64 -> scratch spills ->
// HBM write explosion (R6/R8/R9 all had VGPR=64 + WRITE 62-92 MB).
__global__ __launch_bounds__(256, 3) void ssim_scale0_kernel(
    const float* __restrict__ X, const float* __restrict__ Y,
    const float* __restrict__ kern, float* __restrict__ part,
    float* __restrict__ X1, float* __restrict__ Y1,
    float* __restrict__ X2, float* __restrict__ Y2,
    float* __restrict__ X3, float* __restrict__ Y3,
    float* __restrict__ X4, float* __restrict__ Y4)
{
    const int H = 512, W = 512;
    const int nc  = blockIdx.z;
    const int ch  = nc % 3;
    const int gx0 = blockIdx.x * TW;
    const int gy0 = blockIdx.y * TH;
    const int tid = threadIdx.x;

    __shared__ __align__(16) float vbuf[4][TH][IWC];
    __shared__ float pl2[2][8][16];
    __shared__ float pl3[2][4][8];
    __shared__ float red[8];

    float k[KS];
#pragma unroll
    for (int t = 0; t < KS; ++t) k[t] = kern[ch * KS + t];

    const float* Xp = X + (size_t)nc * H * W;
    const float* Yp = Y + (size_t)nc * H * W;

    const bool guard = (gx0 + IWC > W) || (gy0 + TH + 11 > H);
    if (guard) v_pass_pool<true >(Xp, Yp, k, gx0, gy0, tid, (vbuf_t*)vbuf, pl2, X1, Y1, X2, Y2, nc);
    else       v_pass_pool<false>(Xp, Yp, k, gx0, gy0, tid, (vbuf_t*)vbuf, pl2, X1, Y1, X2, Y2, nc);
    __syncthreads();

    float ss_acc = 0.f, cs_acc = 0.f;
    if (guard) h_pass<true >(k, H, W, gx0, gy0, tid, (vbuf_t*)vbuf, ss_acc, cs_acc);
    else       h_pass<false>(k, H, W, gx0, gy0, tid, (vbuf_t*)vbuf, ss_acc, cs_acc);

    // ---- levels 3&4 from tiny LDS staging ----
    if (tid < 64) {
        const int W8 = W >> 3;
        int a = tid >> 5, q = tid & 31;
        int r3 = q >> 3, c3 = q & 7;
        const float (*s)[16] = pl2[a];
        float v = 0.25f * (s[2*r3][2*c3] + s[2*r3][2*c3 + 1] +
                           s[2*r3 + 1][2*c3] + s[2*r3 + 1][2*c3 + 1]);
        pl3[a][r3][c3] = v;
        size_t d3 = (size_t)nc * W8 * W8 + (size_t)((gy0 >> 3) + r3) * W8 + ((gx0 >> 3) + c3);
        (a ? Y3 : X3)[d3] = v;
    }
    __syncthreads();
    if (tid < 16) {
        const int W16 = W >> 4;
        int a = tid >> 3, q = tid & 7;
        int r4 = q >> 2, c4 = q & 3;
        const float (*s)[8] = pl3[a];
        float v = 0.25f * (s[2*r4][2*c4] + s[2*r4][2*c4 + 1] +
                           s[2*r4 + 1][2*c4] + s[2*r4 + 1][2*c4 + 1]);
        size_t d4 = (size_t)nc * W16 * W16 + (size_t)((gy0 >> 4) + r4) * W16 + ((gx0 >> 4) + c4);
        (a ? Y4 : X4)[d4] = v;
    }

    int t = blockIdx.y * gridDim.x + blockIdx.x;
    block_reduce_store(ss_acc, cs_acc, tid, red,
                       part + ((size_t)nc * (gridDim.x * gridDim.y) + t) * 2);
}

// ================= merged scales 1-4 ======================================
__global__ __launch_bounds__(256, 3) void ssim_rest_kernel(
    const float* __restrict__ x1, const float* __restrict__ y1,
    const float* __restrict__ x2, const float* __restrict__ y2,
    const float* __restrict__ x3, const float* __restrict__ y3,
    const float* __restrict__ x4, const float* __restrict__ y4,
    const float* __restrict__ kern, float* __restrict__ part)
{
    const int z = blockIdx.z;
    const int tid = threadIdx.x;

    int img, bx, by, H, poff, nt, gw;
    const float *Xs, *Ys;
    if (z < 768)       { int r = z;        img = r >> 5; int t = r & 31; bx = t & 3; by = t >> 2; H = 256; Xs = x1; Ys = y1; poff = 6144; nt = 32; gw = 4; }
    else if (z < 960)  { int r = z - 768;  img = r >> 3; int t = r & 7;  bx = t & 1; by = t >> 1; H = 128; Xs = x2; Ys = y2; poff = 7680; nt = 8;  gw = 2; }
    else if (z < 1008) { int r = z - 960;  img = r >> 1; bx = 0; by = r & 1;         H = 64;  Xs = x3; Ys = y3; poff = 8064; nt = 2;  gw = 1; }
    else               { img = z - 1008;   bx = 0; by = 0;                           H = 32;  Xs = x4; Ys = y4; poff = 8160; nt = 1;  gw = 1; }
    const int W = H;
    const int gx0 = bx * TW, gy0 = by * TH;
    const int ch = img % 3;

    __shared__ __align__(16) float vbuf[4][TH][IWC];
    __shared__ float red[8];

    float k[KS];
#pragma unroll
    for (int t = 0; t < KS; ++t) k[t] = kern[ch * KS + t];

    const float* Xp = Xs + (size_t)img * H * W;
    const float* Yp = Ys + (size_t)img * H * W;

    const bool guard = (gx0 + IWC > W) || (gy0 + TH + 11 > H);
    if (guard) v_pass<true >(Xp, Yp, k, H, W, gx0, gy0, tid, (vbuf_t*)vbuf);
    else       v_pass<false>(Xp, Yp, k, H, W, gx0, gy0, tid, (vbuf_t*)vbuf);
    __syncthreads();

    float ss_acc = 0.f, cs_acc = 0.f;
    if (guard) h_pass<true >(k, H, W, gx0, gy0, tid, (vbuf_t*)vbuf, ss_acc, cs_acc);
    else       h_pass<false>(k, H, W, gx0, gy0, tid, (vbuf_t*)vbuf, ss_acc, cs_acc);

    int tl = by * gw + bx;
    block_reduce_store(ss_acc, cs_acc, tid, red,
                       part + poff + ((size_t)img * nt + tl) * 2);
}

// ================= finalize ==============================================
__global__ __launch_bounds__(256) void finalize_kernel(
    const float* __restrict__ part, const float* __restrict__ wts,
    float* __restrict__ out)
{
    __shared__ float smean[NCH][5];
    __shared__ float prods[NCH];
    const int ntiles[5] = {128, 32, 8, 2, 1};
    const int bases[5]  = {0, 6144, 7680, 8064, 8160};
    const float counts[5] = {252004.f, 60516.f, 13924.f, 2916.f, 484.f};
    int tid = threadIdx.x;

    for (int p = tid; p < NCH * 5; p += blockDim.x) {
        int s = p % 5, nc = p / 5;
        int nt = ntiles[s];
        const float* base = part + bases[s] + (size_t)nc * nt * 2;
        int sel = (s == 4) ? 0 : 1;
        float acc = 0.f;
        for (int t = 0; t < nt; ++t) acc += base[t * 2 + sel];
        smean[nc][s] = acc / counts[s];
    }
    __syncthreads();
    if (tid < NCH) {
        float pr = 1.f;
#pragma unroll
        for (int s = 0; s < 5; ++s) {
            float v = fmaxf(smean[tid][s], 0.f);
            pr *= powf(v, wts[s]);
        }
        prods[tid] = pr;
    }
    __syncthreads();
    if (tid == 0) {
        float m = 0.f;
        for (int i = 0; i < NCH; ++i) m += prods[i];
        out[0] = m / (float)NCH;
    }
}

extern "C" void kernel_launch(void* const* d_in, const int* in_sizes, int n_in,
                              void* d_out, int out_size, void* d_ws, size_t ws_size,
                              hipStream_t stream)
{
    const float* x    = (const float*)d_in[0];
    const float* y    = (const float*)d_in[1];
    const float* kern = (const float*)d_in[2];
    const float* wts  = (const float*)d_in[3];
    float* out = (float*)d_out;
    float* ws  = (float*)d_ws;

    size_t o = 0;
    float* x1 = ws + o; o += (size_t)NCH * 256 * 256;
    float* y1 = ws + o; o += (size_t)NCH * 256 * 256;
    float* x2 = ws + o; o += (size_t)NCH * 128 * 128;
    float* y2 = ws + o; o += (size_t)NCH * 128 * 128;
    float* x3 = ws + o; o += (size_t)NCH * 64 * 64;
    float* y3 = ws + o; o += (size_t)NCH * 64 * 64;
    float* x4 = ws + o; o += (size_t)NCH * 32 * 32;
    float* y4 = ws + o; o += (size_t)NCH * 32 * 32;
    float* part = ws + o;  // 8208 floats

    ssim_scale0_kernel<<<dim3(8, 16, NCH), 256, 0, stream>>>(
        x, y, kern, part, x1, y1, x2, y2, x3, y3, x4, y4);

    ssim_rest_kernel<<<dim3(1, 1, 1032), 256, 0, stream>>>(
        x1, y1, x2, y2, x3, y3, x4, y4, kern, part);

    finalize_kernel<<<1, 256, 0, stream>>>(part, wts, out);
}

// Round 12
// 67.547 us; speedup vs baseline: 1.1854x; 1.1854x over previous
//
#include <hip/hip_runtime.h>

#define NCH 24
#define KS 11
#define TH 32          // output rows per tile
#define TW 64          // output cols per tile
#define IWC 76         // LDS col stride (>= TW+10+2, mult of 4)

typedef float f32x2 __attribute__((ext_vector_type(2)));
typedef float vbuf_t[TH][IWC];   // one field: 32 x 76

// ===== core tile: vertical-first sep-conv (4 fields, packed f32x2) + SSIM =
// fields: 0 = x, 1 = y, 2 = xx+yy, 3 = xy  (packed as (0,1) and (2,3))
// Rotating 10-deep register prefetch keeps ~20 loads in flight.
// POOL: level-1 pooling into pl[0..1023] pre-barrier (L2-hot re-read; OK at
// 3 blocks/CU — R7/R10 measured FETCH 35.5 MB clean).
template<bool GUARD, bool POOL>
__device__ __forceinline__ void ssim_tile(
    const float* __restrict__ Xp, const float* __restrict__ Yp,
    const float* __restrict__ k, int H, int W, int gx0, int gy0, int tid,
    vbuf_t* vbuf, float* pl, float& ss_acc, float& cs_acc)
{
    // ---- vertical pass: 3 row-groups x 76 cols = 228 threads, 11 v-rows each
    if (tid < 3 * IWC) {
        const int c  = tid % IWC;
        const int rg = tid / IWC;
        const int r0 = rg * 11;              // v-rows r0..r0+10 (row 32 discarded)
        const int gc = gx0 + c;
        const bool cok = (!GUARD) || (gc < W);

        f32x2 a01[11], a23[11];
#pragma unroll
        for (int i = 0; i < 11; ++i) {
            a01[i] = (f32x2){0.f, 0.f};
            a23[i] = (f32x2){0.f, 0.f};
        }

        const float* xptr = Xp + (size_t)(gy0 + r0) * W + gc;
        const float* yptr = Yp + (size_t)(gy0 + r0) * W + gc;

        // prologue: rows 0..9 into rotating buffer
        float xr[10], yr[10];
#pragma unroll
        for (int i = 0; i < 10; ++i) {
            if (GUARD) {
                const int gy = gy0 + r0 + i;
                xr[i] = 0.f; yr[i] = 0.f;
                if (cok && gy < H) { xr[i] = xptr[0]; yr[i] = yptr[0]; }
            } else {
                xr[i] = xptr[0]; yr[i] = yptr[0];
            }
            xptr += W; yptr += W;
        }

#pragma unroll
        for (int ri = 0; ri < 21; ++ri) {
            const int s = ri % 10;           // static under full unroll
            const float xv = xr[s], yv = yr[s];
            if (ri + 10 < 21) {              // prefetch row ri+10 into slot s
                if (GUARD) {
                    const int gy = gy0 + r0 + ri + 10;
                    xr[s] = 0.f; yr[s] = 0.f;
                    if (cok && gy < H) { xr[s] = xptr[0]; yr[s] = yptr[0]; }
                } else {
                    xr[s] = xptr[0]; yr[s] = yptr[0];
                }
                xptr += W; yptr += W;
            }

            f32x2 vxy, vsx;
            vxy.x = xv; vxy.y = yv;
            vsx.x = fmaf(yv, yv, xv * xv);   // xx+yy
            vsx.y = xv * yv;                 // xy
#pragma unroll
            for (int rv = 0; rv < 11; ++rv) {
                if (rv < (ri > 10 ? ri - 10 : 0)) continue;   // compile-time folded
                if (rv > (ri < 10 ? ri : 10)) continue;
                const float kt = k[ri - rv];
                f32x2 kv; kv.x = kt; kv.y = kt;
                a01[rv] += kv * vxy;         // v_pk_fma_f32 candidates
                a23[rv] += kv * vsx;
            }
        }
#pragma unroll
        for (int rv = 0; rv < 11; ++rv) {
            const int r = r0 + rv;
            if (r < TH) {
                vbuf[0][r][c] = a01[rv].x;
                vbuf[1][r][c] = a01[rv].y;
                vbuf[2][r][c] = a23[rv].x;
                vbuf[3][r][c] = a23[rv].y;
            }
        }
    }

    // ---- level-1 2x2 pooling while input lines are L2-hot (pre-barrier) ----
    if (POOL) {
        for (int p = tid; p < 512; p += 256) {      // 16r x 32c per array
            int pr = p >> 5, pc = p & 31;
            int sr = gy0 + 2 * pr, sc = gx0 + 2 * pc;
            const float* xb = Xp + (size_t)sr * W + sc;
            const float* yb = Yp + (size_t)sr * W + sc;
            pl[p]       = 0.25f * (xb[0] + xb[1] + xb[W] + xb[W + 1]);
            pl[512 + p] = 0.25f * (yb[0] + yb[1] + yb[W] + yb[W + 1]);
        }
    }
    __syncthreads();

    // ---- horizontal pass: b128 LDS reads + packed conv + SSIM
    const float c1 = 1e-4f, c2 = 9e-4f;
    const int row = tid >> 3;
    const int cg  = tid & 7;
    const int c0  = cg * 8;
    const bool rowok = (!GUARD) || ((gy0 + row) <= (H - KS));

    f32x2 h01[8], h23[8];
#pragma unroll
    for (int j = 0; j < 8; ++j) {
        h01[j] = (f32x2){0.f, 0.f};
        h23[j] = (f32x2){0.f, 0.f};
    }

#pragma unroll
    for (int fp = 0; fp < 2; ++fp) {         // field pairs (0,1) and (2,3)
        const float4* pA = reinterpret_cast<const float4*>(&vbuf[2 * fp][row][c0]);
        const float4* pB = reinterpret_cast<const float4*>(&vbuf[2 * fp + 1][row][c0]);
        float4 a0 = pA[0], a1 = pA[1], a2 = pA[2], a3 = pA[3], a4 = pA[4];
        float4 b0 = pB[0], b1 = pB[1], b2 = pB[2], b3 = pB[3], b4 = pB[4];
        float va[20] = {a0.x,a0.y,a0.z,a0.w, a1.x,a1.y,a1.z,a1.w,
                        a2.x,a2.y,a2.z,a2.w, a3.x,a3.y,a3.z,a3.w,
                        a4.x,a4.y,a4.z,a4.w};
        float vb[20] = {b0.x,b0.y,b0.z,b0.w, b1.x,b1.y,b1.z,b1.w,
                        b2.x,b2.y,b2.z,b2.w, b3.x,b3.y,b3.z,b3.w,
                        b4.x,b4.y,b4.z,b4.w};
        f32x2 w[20];
#pragma unroll
        for (int i = 0; i < 20; ++i) { w[i].x = va[i]; w[i].y = vb[i]; }

        f32x2* h2 = (fp == 0) ? h01 : h23;
#pragma unroll
        for (int j = 0; j < 8; ++j)
#pragma unroll
            for (int t = 0; t < KS; ++t) {
                f32x2 kv; kv.x = k[t]; kv.y = k[t];
                h2[j] += kv * w[j + t];      // v_pk_fma_f32 candidates
            }
    }

#pragma unroll
    for (int j = 0; j < 8; ++j) {
        bool ok = rowok && ((!GUARD) || ((gx0 + c0 + j) <= (W - KS)));
        if (ok) {
            float mx = h01[j].x, my = h01[j].y;
            float S = h23[j].x, vxy = h23[j].y;
            float mxx = mx * mx, myy = my * my, mxy = mx * my;
            float msum = mxx + myy;
            float sxy = vxy - mxy, ssum = S - msum;
            float cs = (2.f * sxy + c2) * __builtin_amdgcn_rcpf(ssum + c2);
            float ssv = (2.f * mxy + c1) * __builtin_amdgcn_rcpf(msum + c1) * cs;
            ss_acc += ssv; cs_acc += cs;
        }
    }
}

__device__ __forceinline__ void block_reduce_store(
    float ss_acc, float cs_acc, int tid, float* red, float* slot)
{
    for (int off = 32; off > 0; off >>= 1) {
        ss_acc += __shfl_down(ss_acc, off);
        cs_acc += __shfl_down(cs_acc, off);
    }
    const int wave = tid >> 6;
    if ((tid & 63) == 0) { red[wave * 2] = ss_acc; red[wave * 2 + 1] = cs_acc; }
    __syncthreads();
    if (tid == 0) {
        slot[0] = red[0] + red[2] + red[4] + red[6];
        slot[1] = red[1] + red[3] + red[5] + red[7];
    }
}

// ================= scale-0: SSIM + full pooled-pyramid epilogue ===========
// LB(256,3): LB(256,4) caps VGPR at 64 -> scratch spills -> HBM explosion
// (R6/R8/R9: VGPR=64 + WRITE 62-92 MB). Occupancy >3 blocks never observed
// even with LDS<=40K (R11) -> stay at 3 and optimize issue rate instead.
__global__ __launch_bounds__(256, 3) void ssim_scale0_kernel(
    const float* __restrict__ X, const float* __restrict__ Y,
    const float* __restrict__ kern, float* __restrict__ part,
    float* __restrict__ X1, float* __restrict__ Y1,
    float* __restrict__ X2, float* __restrict__ Y2,
    float* __restrict__ X3, float* __restrict__ Y3,
    float* __restrict__ X4, float* __restrict__ Y4)
{
    const int H = 512, W = 512;
    const int nc  = blockIdx.z;
    const int ch  = nc % 3;
    const int gx0 = blockIdx.x * TW;
    const int gy0 = blockIdx.y * TH;
    const int tid = threadIdx.x;

    __shared__ __align__(16) float vbuf[4][TH][IWC];
    __shared__ float pl[1344];   // lvl1: [0,1024) lvl2: [1024,1280) lvl3: [1280,1344)
    __shared__ float red[8];

    float k[KS];
#pragma unroll
    for (int t = 0; t < KS; ++t) k[t] = kern[ch * KS + t];

    const float* Xp = X + (size_t)nc * H * W;
    const float* Yp = Y + (size_t)nc * H * W;

    float ss_acc = 0.f, cs_acc = 0.f;
    const bool guard = (gx0 + IWC > W) || (gy0 + TH + 11 > H);
    if (guard) ssim_tile<true , true>(Xp, Yp, k, H, W, gx0, gy0, tid, (vbuf_t*)vbuf, pl, ss_acc, cs_acc);
    else       ssim_tile<false, true>(Xp, Yp, k, H, W, gx0, gy0, tid, (vbuf_t*)vbuf, pl, ss_acc, cs_acc);

    // ---- write level 1 to global + build levels 2-4 from LDS (no global re-read)
    {
        const int W2 = W >> 1;
        for (int p = tid; p < 512; p += 256) {
            int pr = p >> 5, pc = p & 31;
            size_t di = (size_t)nc * W2 * W2 + (size_t)((gy0 >> 1) + pr) * W2 + ((gx0 >> 1) + pc);
            X1[di] = pl[p];
            Y1[di] = pl[512 + p];
        }
    }
    {
        const int W4 = W >> 2;                         // level 2: 8r x 16c per array
        int a = tid >> 7, p = tid & 127;
        int pr = p >> 4, pc = p & 15;
        const float* src = pl + a * 512;
        float v = 0.25f * (src[(2*pr)*32 + 2*pc] + src[(2*pr)*32 + 2*pc + 1] +
                           src[(2*pr+1)*32 + 2*pc] + src[(2*pr+1)*32 + 2*pc + 1]);
        pl[1024 + a * 128 + p] = v;
        size_t di = (size_t)nc * W4 * W4 + (size_t)((gy0 >> 2) + pr) * W4 + ((gx0 >> 2) + pc);
        (a ? Y2 : X2)[di] = v;
    }
    __syncthreads();
    if (tid < 64) {
        const int W8 = W >> 3;                         // level 3: 4r x 8c per array
        int a = tid >> 5, p = tid & 31;
        int pr = p >> 3, pc = p & 7;
        const float* src = pl + 1024 + a * 128;
        float v = 0.25f * (src[(2*pr)*16 + 2*pc] + src[(2*pr)*16 + 2*pc + 1] +
                           src[(2*pr+1)*16 + 2*pc] + src[(2*pr+1)*16 + 2*pc + 1]);
        pl[1280 + a * 32 + p] = v;
        size_t di = (size_t)nc * W8 * W8 + (size_t)((gy0 >> 3) + pr) * W8 + ((gx0 >> 3) + pc);
        (a ? Y3 : X3)[di] = v;
    }
    __syncthreads();
    if (tid < 16) {
        const int W16 = W >> 4;                        // level 4: 2r x 4c per array
        int a = tid >> 3, p = tid & 7;
        int pr = p >> 2, pc = p & 3;
        const float* src = pl + 1280 + a * 32;
        float v = 0.25f * (src[(2*pr)*8 + 2*pc] + src[(2*pr)*8 + 2*pc + 1] +
                           src[(2*pr+1)*8 + 2*pc] + src[(2*pr+1)*8 + 2*pc + 1]);
        size_t di = (size_t)nc * W16 * W16 + (size_t)((gy0 >> 4) + pr) * W16 + ((gx0 >> 4) + pc);
        (a ? Y4 : X4)[di] = v;
    }

    int t = blockIdx.y * gridDim.x + blockIdx.x;
    block_reduce_store(ss_acc, cs_acc, tid, red,
                       part + ((size_t)nc * (gridDim.x * gridDim.y) + t) * 2);
}

// ================= merged scales 1-4 ======================================
__global__ __launch_bounds__(256, 3) void ssim_rest_kernel(
    const float* __restrict__ x1, const float* __restrict__ y1,
    const float* __restrict__ x2, const float* __restrict__ y2,
    const float* __restrict__ x3, const float* __restrict__ y3,
    const float* __restrict__ x4, const float* __restrict__ y4,
    const float* __restrict__ kern, float* __restrict__ part)
{
    const int z = blockIdx.z;
    const int tid = threadIdx.x;

    int img, bx, by, H, poff, nt, gw;
    const float *Xs, *Ys;
    if (z < 768)       { int r = z;        img = r >> 5; int t = r & 31; bx = t & 3; by = t >> 2; H = 256; Xs = x1; Ys = y1; poff = 6144; nt = 32; gw = 4; }
    else if (z < 960)  { int r = z - 768;  img = r >> 3; int t = r & 7;  bx = t & 1; by = t >> 1; H = 128; Xs = x2; Ys = y2; poff = 7680; nt = 8;  gw = 2; }
    else if (z < 1008) { int r = z - 960;  img = r >> 1; bx = 0; by = r & 1;         H = 64;  Xs = x3; Ys = y3; poff = 8064; nt = 2;  gw = 1; }
    else               { img = z - 1008;   bx = 0; by = 0;                           H = 32;  Xs = x4; Ys = y4; poff = 8160; nt = 1;  gw = 1; }
    const int W = H;
    const int gx0 = bx * TW, gy0 = by * TH;
    const int ch = img % 3;

    __shared__ __align__(16) float vbuf[4][TH][IWC];
    __shared__ float red[8];

    float k[KS];
#pragma unroll
    for (int t = 0; t < KS; ++t) k[t] = kern[ch * KS + t];

    const float* Xp = Xs + (size_t)img * H * W;
    const float* Yp = Ys + (size_t)img * H * W;

    float ss_acc = 0.f, cs_acc = 0.f;
    const bool guard = (gx0 + IWC > W) || (gy0 + TH + 11 > H);
    if (guard) ssim_tile<true , false>(Xp, Yp, k, H, W, gx0, gy0, tid, (vbuf_t*)vbuf, nullptr, ss_acc, cs_acc);
    else       ssim_tile<false, false>(Xp, Yp, k, H, W, gx0, gy0, tid, (vbuf_t*)vbuf, nullptr, ss_acc, cs_acc);

    int tl = by * gw + bx;
    block_reduce_store(ss_acc, cs_acc, tid, red,
                       part + poff + ((size_t)img * nt + tl) * 2);
}

// ================= finalize ==============================================
__global__ __launch_bounds__(256) void finalize_kernel(
    const float* __restrict__ part, const float* __restrict__ wts,
    float* __restrict__ out)
{
    __shared__ float smean[NCH][5];
    __shared__ float prods[NCH];
    const int ntiles[5] = {128, 32, 8, 2, 1};
    const int bases[5]  = {0, 6144, 7680, 8064, 8160};
    const float counts[5] = {252004.f, 60516.f, 13924.f, 2916.f, 484.f};
    int tid = threadIdx.x;

    for (int p = tid; p < NCH * 5; p += blockDim.x) {
        int s = p % 5, nc = p / 5;
        int nt = ntiles[s];
        const float* base = part + bases[s] + (size_t)nc * nt * 2;
        int sel = (s == 4) ? 0 : 1;   // ss for last scale, cs otherwise
        float acc = 0.f;
        for (int t = 0; t < nt; ++t) acc += base[t * 2 + sel];
        smean[nc][s] = acc / counts[s];
    }
    __syncthreads();
    if (tid < NCH) {
        float pr = 1.f;
#pragma unroll
        for (int s = 0; s < 5; ++s) {
            float v = fmaxf(smean[tid][s], 0.f);
            pr *= powf(v, wts[s]);
        }
        prods[tid] = pr;
    }
    __syncthreads();
    if (tid == 0) {
        float m = 0.f;
        for (int i = 0; i < NCH; ++i) m += prods[i];
        out[0] = m / (float)NCH;
    }
}

extern "C" void kernel_launch(void* const* d_in, const int* in_sizes, int n_in,
                              void* d_out, int out_size, void* d_ws, size_t ws_size,
                              hipStream_t stream)
{
    const float* x    = (const float*)d_in[0];
    const float* y    = (const float*)d_in[1];
    const float* kern = (const float*)d_in[2];
    const float* wts  = (const float*)d_in[3];
    float* out = (float*)d_out;
    float* ws  = (float*)d_ws;

    size_t o = 0;
    float* x1 = ws + o; o += (size_t)NCH * 256 * 256;
    float* y1 = ws + o; o += (size_t)NCH * 256 * 256;
    float* x2 = ws + o; o += (size_t)NCH * 128 * 128;
    float* y2 = ws + o; o += (size_t)NCH * 128 * 128;
    float* x3 = ws + o; o += (size_t)NCH * 64 * 64;
    float* y3 = ws + o; o += (size_t)NCH * 64 * 64;
    float* x4 = ws + o; o += (size_t)NCH * 32 * 32;
    float* y4 = ws + o; o += (size_t)NCH * 32 * 32;
    float* part = ws + o;  // 8208 floats

    ssim_scale0_kernel<<<dim3(8, 16, NCH), 256, 0, stream>>>(
        x, y, kern, part, x1, y1, x2, y2, x3, y3, x4, y4);

    ssim_rest_kernel<<<dim3(1, 1, 1032), 256, 0, stream>>>(
        x1, y1, x2, y2, x3, y3, x4, y4, kern, part);

    finalize_kernel<<<1, 256, 0, stream>>>(part, wts, out);
}

// Round 13
// 64.845 us; speedup vs baseline: 1.2348x; 1.0417x over previous
//
#include <hip/hip_runtime.h>

#define NCH 24
#define KS 11
#define TH 32          // output rows per tile
#define TW 64          // output cols per tile
#define IWC 76         // LDS col stride (>= TW+10+2, mult of 4)

typedef float f32x2 __attribute__((ext_vector_type(2)));
typedef float vbuf_t[TH][IWC];   // one field: 32 x 76

// ===== vertical pass: packed f32x2 conv, rotating 10-deep prefetch ========
// fields: 0 = x, 1 = y, 2 = xx+yy, 3 = xy  (packed as (0,1) and (2,3))
template<bool GUARD>
__device__ __forceinline__ void v_pass_pk(
    const float* __restrict__ Xp, const float* __restrict__ Yp,
    const float* __restrict__ k, int H, int W, int gx0, int gy0, int tid,
    vbuf_t* vbuf)
{
    if (tid < 3 * IWC) {
        const int c  = tid % IWC;
        const int rg = tid / IWC;
        const int r0 = rg * 11;              // v-rows r0..r0+10 (row 32 discarded)
        const int gc = gx0 + c;
        const bool cok = (!GUARD) || (gc < W);

        f32x2 a01[11], a23[11];
#pragma unroll
        for (int i = 0; i < 11; ++i) {
            a01[i] = (f32x2){0.f, 0.f};
            a23[i] = (f32x2){0.f, 0.f};
        }

        const float* xptr = Xp + (size_t)(gy0 + r0) * W + gc;
        const float* yptr = Yp + (size_t)(gy0 + r0) * W + gc;

        float xr[10], yr[10];
#pragma unroll
        for (int i = 0; i < 10; ++i) {
            if (GUARD) {
                const int gy = gy0 + r0 + i;
                xr[i] = 0.f; yr[i] = 0.f;
                if (cok && gy < H) { xr[i] = xptr[0]; yr[i] = yptr[0]; }
            } else {
                xr[i] = xptr[0]; yr[i] = yptr[0];
            }
            xptr += W; yptr += W;
        }

#pragma unroll
        for (int ri = 0; ri < 21; ++ri) {
            const int s = ri % 10;           // static under full unroll
            const float xv = xr[s], yv = yr[s];
            if (ri + 10 < 21) {
                if (GUARD) {
                    const int gy = gy0 + r0 + ri + 10;
                    xr[s] = 0.f; yr[s] = 0.f;
                    if (cok && gy < H) { xr[s] = xptr[0]; yr[s] = yptr[0]; }
                } else {
                    xr[s] = xptr[0]; yr[s] = yptr[0];
                }
                xptr += W; yptr += W;
            }

            f32x2 vxy, vsx;
            vxy.x = xv; vxy.y = yv;
            vsx.x = fmaf(yv, yv, xv * xv);   // xx+yy
            vsx.y = xv * yv;                 // xy
#pragma unroll
            for (int rv = 0; rv < 11; ++rv) {
                if (rv < (ri > 10 ? ri - 10 : 0)) continue;   // compile-time folded
                if (rv > (ri < 10 ? ri : 10)) continue;
                const float kt = k[ri - rv];
                f32x2 kv; kv.x = kt; kv.y = kt;
                a01[rv] += kv * vxy;         // v_pk_fma_f32
                a23[rv] += kv * vsx;
            }
        }
#pragma unroll
        for (int rv = 0; rv < 11; ++rv) {
            const int r = r0 + rv;
            if (r < TH) {
                vbuf[0][r][c] = a01[rv].x;
                vbuf[1][r][c] = a01[rv].y;
                vbuf[2][r][c] = a23[rv].x;
                vbuf[3][r][c] = a23[rv].y;
            }
        }
    }
}

// ===== horizontal pass: b128 LDS reads + packed conv + SSIM ===============
template<bool GUARD>
__device__ __forceinline__ void h_pass_pk(
    const float* __restrict__ k, int H, int W, int gx0, int gy0, int tid,
    vbuf_t* vbuf, float& ss_acc, float& cs_acc)
{
    const float c1 = 1e-4f, c2 = 9e-4f;
    const int row = tid >> 3;
    const int cg  = tid & 7;
    const int c0  = cg * 8;
    const bool rowok = (!GUARD) || ((gy0 + row) <= (H - KS));

    f32x2 h01[8], h23[8];
#pragma unroll
    for (int j = 0; j < 8; ++j) {
        h01[j] = (f32x2){0.f, 0.f};
        h23[j] = (f32x2){0.f, 0.f};
    }

#pragma unroll
    for (int fp = 0; fp < 2; ++fp) {         // field pairs (0,1) and (2,3)
        const float4* pA = reinterpret_cast<const float4*>(&vbuf[2 * fp][row][c0]);
        const float4* pB = reinterpret_cast<const float4*>(&vbuf[2 * fp + 1][row][c0]);
        float4 a0 = pA[0], a1 = pA[1], a2 = pA[2], a3 = pA[3], a4 = pA[4];
        float4 b0 = pB[0], b1 = pB[1], b2 = pB[2], b3 = pB[3], b4 = pB[4];
        float va[20] = {a0.x,a0.y,a0.z,a0.w, a1.x,a1.y,a1.z,a1.w,
                        a2.x,a2.y,a2.z,a2.w, a3.x,a3.y,a3.z,a3.w,
                        a4.x,a4.y,a4.z,a4.w};
        float vb[20] = {b0.x,b0.y,b0.z,b0.w, b1.x,b1.y,b1.z,b1.w,
                        b2.x,b2.y,b2.z,b2.w, b3.x,b3.y,b3.z,b3.w,
                        b4.x,b4.y,b4.z,b4.w};
        f32x2 w[20];
#pragma unroll
        for (int i = 0; i < 20; ++i) { w[i].x = va[i]; w[i].y = vb[i]; }

        f32x2* h2 = (fp == 0) ? h01 : h23;
#pragma unroll
        for (int j = 0; j < 8; ++j)
#pragma unroll
            for (int t = 0; t < KS; ++t) {
                f32x2 kv; kv.x = k[t]; kv.y = k[t];
                h2[j] += kv * w[j + t];      // v_pk_fma_f32
            }
    }

#pragma unroll
    for (int j = 0; j < 8; ++j) {
        bool ok = rowok && ((!GUARD) || ((gx0 + c0 + j) <= (W - KS)));
        if (ok) {
            float mx = h01[j].x, my = h01[j].y;
            float S = h23[j].x, vxy = h23[j].y;
            float mxx = mx * mx, myy = my * my, mxy = mx * my;
            float msum = mxx + myy;
            float sxy = vxy - mxy, ssum = S - msum;
            float cs = (2.f * sxy + c2) * __builtin_amdgcn_rcpf(ssum + c2);
            float ssv = (2.f * mxy + c1) * __builtin_amdgcn_rcpf(msum + c1) * cs;
            ss_acc += ssv; cs_acc += cs;
        }
    }
}

__device__ __forceinline__ void block_reduce_store(
    float ss_acc, float cs_acc, int tid, float* red, float* slot)
{
    for (int off = 32; off > 0; off >>= 1) {
        ss_acc += __shfl_down(ss_acc, off);
        cs_acc += __shfl_down(cs_acc, off);
    }
    const int wave = tid >> 6;
    if ((tid & 63) == 0) { red[wave * 2] = ss_acc; red[wave * 2 + 1] = cs_acc; }
    __syncthreads();
    if (tid == 0) {
        slot[0] = red[0] + red[2] + red[4] + red[6];
        slot[1] = red[1] + red[3] + red[5] + red[7];
    }
}

// ================= scale-0: SSIM + pooled pyramid (pl in registers) =======
// LDS = vbuf 38912 + red 32 = 38944 B -> 4 blocks/CU fit (4x < 160 KiB).
// Level-1 pooled values held in 4 regs/thread: loaded PRE-barrier (L2-hot,
// avoids R6's cold re-read) and staged into reused vbuf AFTER h-pass
// (avoids R11's v-pass shuffle slowdown). LB(256,3) NOT (256,4): VGPR cap
// 64 causes scratch spills (R6/R8/R9: WRITE 62-92 MB).
__global__ __launch_bounds__(256, 3) void ssim_scale0_kernel(
    const float* __restrict__ X, const float* __restrict__ Y,
    const float* __restrict__ kern, float* __restrict__ part,
    float* __restrict__ X1, float* __restrict__ Y1,
    float* __restrict__ X2, float* __restrict__ Y2,
    float* __restrict__ X3, float* __restrict__ Y3,
    float* __restrict__ X4, float* __restrict__ Y4)
{
    const int H = 512, W = 512;
    const int nc  = blockIdx.z;
    const int ch  = nc % 3;
    const int gx0 = blockIdx.x * TW;
    const int gy0 = blockIdx.y * TH;
    const int tid = threadIdx.x;

    __shared__ __align__(16) float vbuf[4][TH][IWC];
    __shared__ float red[8];

    float k[KS];
#pragma unroll
    for (int t = 0; t < KS; ++t) k[t] = kern[ch * KS + t];

    const float* Xp = X + (size_t)nc * H * W;
    const float* Yp = Y + (size_t)nc * H * W;

    const bool guard = (gx0 + IWC > W) || (gy0 + TH + 11 > H);
    if (guard) v_pass_pk<true >(Xp, Yp, k, H, W, gx0, gy0, tid, (vbuf_t*)vbuf);
    else       v_pass_pk<false>(Xp, Yp, k, H, W, gx0, gy0, tid, (vbuf_t*)vbuf);

    // ---- level-1 pooling into REGISTERS + global write (pre-barrier, hot) --
    float plx[2], ply[2];
    {
        const int W2 = W >> 1;
#pragma unroll
        for (int i = 0; i < 2; ++i) {
            int p = tid + i * 256;           // 16r x 32c pooled tile
            int pr = p >> 5, pc = p & 31;
            int sr = gy0 + 2 * pr, sc = gx0 + 2 * pc;
            const float* xb = Xp + (size_t)sr * W + sc;
            const float* yb = Yp + (size_t)sr * W + sc;
            plx[i] = 0.25f * (xb[0] + xb[1] + xb[W] + xb[W + 1]);
            ply[i] = 0.25f * (yb[0] + yb[1] + yb[W] + yb[W + 1]);
            size_t di = (size_t)nc * W2 * W2 + (size_t)((gy0 >> 1) + pr) * W2 + ((gx0 >> 1) + pc);
            X1[di] = plx[i];
            Y1[di] = ply[i];
        }
    }
    __syncthreads();

    float ss_acc = 0.f, cs_acc = 0.f;
    if (guard) h_pass_pk<true >(k, H, W, gx0, gy0, tid, (vbuf_t*)vbuf, ss_acc, cs_acc);
    else       h_pass_pk<false>(k, H, W, gx0, gy0, tid, (vbuf_t*)vbuf, ss_acc, cs_acc);
    __syncthreads();                         // all h-pass vbuf reads done

    // ---- stage lvl1 regs into reused vbuf; build levels 2-4 from LDS ------
    float* pb = (float*)vbuf;                // [0,512)=x [512,1024)=y
    pb[tid]        = plx[0];
    pb[tid + 256]  = plx[1];
    pb[512 + tid]  = ply[0];
    pb[768 + tid]  = ply[1];
    __syncthreads();
    {
        const int W4 = W >> 2;               // level 2: 8r x 16c per array
        int a = tid >> 7, p = tid & 127;
        int pr = p >> 4, pc = p & 15;
        const float* src = pb + a * 512;
        float v = 0.25f * (src[(2*pr)*32 + 2*pc] + src[(2*pr)*32 + 2*pc + 1] +
                           src[(2*pr+1)*32 + 2*pc] + src[(2*pr+1)*32 + 2*pc + 1]);
        pb[1024 + a * 128 + p] = v;
        size_t di = (size_t)nc * W4 * W4 + (size_t)((gy0 >> 2) + pr) * W4 + ((gx0 >> 2) + pc);
        (a ? Y2 : X2)[di] = v;
    }
    __syncthreads();
    if (tid < 64) {
        const int W8 = W >> 3;               // level 3: 4r x 8c per array
        int a = tid >> 5, p = tid & 31;
        int pr = p >> 3, pc = p & 7;
        const float* src = pb + 1024 + a * 128;
        float v = 0.25f * (src[(2*pr)*16 + 2*pc] + src[(2*pr)*16 + 2*pc + 1] +
                           src[(2*pr+1)*16 + 2*pc] + src[(2*pr+1)*16 + 2*pc + 1]);
        pb[1280 + a * 32 + p] = v;
        size_t di = (size_t)nc * W8 * W8 + (size_t)((gy0 >> 3) + pr) * W8 + ((gx0 >> 3) + pc);
        (a ? Y3 : X3)[di] = v;
    }
    __syncthreads();
    if (tid < 16) {
        const int W16 = W >> 4;              // level 4: 2r x 4c per array
        int a = tid >> 3, p = tid & 7;
        int pr = p >> 2, pc = p & 3;
        const float* src = pb + 1280 + a * 32;
        float v = 0.25f * (src[(2*pr)*8 + 2*pc] + src[(2*pr)*8 + 2*pc + 1] +
                           src[(2*pr+1)*8 + 2*pc] + src[(2*pr+1)*8 + 2*pc + 1]);
        size_t di = (size_t)nc * W16 * W16 + (size_t)((gy0 >> 4) + pr) * W16 + ((gx0 >> 4) + pc);
        (a ? Y4 : X4)[di] = v;
    }

    int t = blockIdx.y * gridDim.x + blockIdx.x;
    block_reduce_store(ss_acc, cs_acc, tid, red,
                       part + ((size_t)nc * (gridDim.x * gridDim.y) + t) * 2);
}

// ================= merged scales 1-4 ======================================
__global__ __launch_bounds__(256, 3) void ssim_rest_kernel(
    const float* __restrict__ x1, const float* __restrict__ y1,
    const float* __restrict__ x2, const float* __restrict__ y2,
    const float* __restrict__ x3, const float* __restrict__ y3,
    const float* __restrict__ x4, const float* __restrict__ y4,
    const float* __restrict__ kern, float* __restrict__ part)
{
    const int z = blockIdx.z;
    const int tid = threadIdx.x;

    int img, bx, by, H, poff, nt, gw;
    const float *Xs, *Ys;
    if (z < 768)       { int r = z;        img = r >> 5; int t = r & 31; bx = t & 3; by = t >> 2; H = 256; Xs = x1; Ys = y1; poff = 6144; nt = 32; gw = 4; }
    else if (z < 960)  { int r = z - 768;  img = r >> 3; int t = r & 7;  bx = t & 1; by = t >> 1; H = 128; Xs = x2; Ys = y2; poff = 7680; nt = 8;  gw = 2; }
    else if (z < 1008) { int r = z - 960;  img = r >> 1; bx = 0; by = r & 1;         H = 64;  Xs = x3; Ys = y3; poff = 8064; nt = 2;  gw = 1; }
    else               { img = z - 1008;   bx = 0; by = 0;                           H = 32;  Xs = x4; Ys = y4; poff = 8160; nt = 1;  gw = 1; }
    const int W = H;
    const int gx0 = bx * TW, gy0 = by * TH;
    const int ch = img % 3;

    __shared__ __align__(16) float vbuf[4][TH][IWC];
    __shared__ float red[8];

    float k[KS];
#pragma unroll
    for (int t = 0; t < KS; ++t) k[t] = kern[ch * KS + t];

    const float* Xp = Xs + (size_t)img * H * W;
    const float* Yp = Ys + (size_t)img * H * W;

    const bool guard = (gx0 + IWC > W) || (gy0 + TH + 11 > H);
    if (guard) v_pass_pk<true >(Xp, Yp, k, H, W, gx0, gy0, tid, (vbuf_t*)vbuf);
    else       v_pass_pk<false>(Xp, Yp, k, H, W, gx0, gy0, tid, (vbuf_t*)vbuf);
    __syncthreads();

    float ss_acc = 0.f, cs_acc = 0.f;
    if (guard) h_pass_pk<true >(k, H, W, gx0, gy0, tid, (vbuf_t*)vbuf, ss_acc, cs_acc);
    else       h_pass_pk<false>(k, H, W, gx0, gy0, tid, (vbuf_t*)vbuf, ss_acc, cs_acc);

    int tl = by * gw + bx;
    block_reduce_store(ss_acc, cs_acc, tid, red,
                       part + poff + ((size_t)img * nt + tl) * 2);
}

// ================= finalize ==============================================
__global__ __launch_bounds__(256) void finalize_kernel(
    const float* __restrict__ part, const float* __restrict__ wts,
    float* __restrict__ out)
{
    __shared__ float smean[NCH][5];
    __shared__ float prods[NCH];
    const int ntiles[5] = {128, 32, 8, 2, 1};
    const int bases[5]  = {0, 6144, 7680, 8064, 8160};
    const float counts[5] = {252004.f, 60516.f, 13924.f, 2916.f, 484.f};
    int tid = threadIdx.x;

    for (int p = tid; p < NCH * 5; p += blockDim.x) {
        int s = p % 5, nc = p / 5;
        int nt = ntiles[s];
        const float* base = part + bases[s] + (size_t)nc * nt * 2;
        int sel = (s == 4) ? 0 : 1;   // ss for last scale, cs otherwise
        float acc = 0.f;
        for (int t = 0; t < nt; ++t) acc += base[t * 2 + sel];
        smean[nc][s] = acc / counts[s];
    }
    __syncthreads();
    if (tid < NCH) {
        float pr = 1.f;
#pragma unroll
        for (int s = 0; s < 5; ++s) {
            float v = fmaxf(smean[tid][s], 0.f);
            pr *= powf(v, wts[s]);
        }
        prods[tid] = pr;
    }
    __syncthreads();
    if (tid == 0) {
        float m = 0.f;
        for (int i = 0; i < NCH; ++i) m += prods[i];
        out[0] = m / (float)NCH;
    }
}

extern "C" void kernel_launch(void* const* d_in, const int* in_sizes, int n_in,
                              void* d_out, int out_size, void* d_ws, size_t ws_size,
                              hipStream_t stream)
{
    const float* x    = (const float*)d_in[0];
    const float* y    = (const float*)d_in[1];
    const float* kern = (const float*)d_in[2];
    const float* wts  = (const float*)d_in[3];
    float* out = (float*)d_out;
    float* ws  = (float*)d_ws;

    size_t o = 0;
    float* x1 = ws + o; o += (size_t)NCH * 256 * 256;
    float* y1 = ws + o; o += (size_t)NCH * 256 * 256;
    float* x2 = ws + o; o += (size_t)NCH * 128 * 128;
    float* y2 = ws + o; o += (size_t)NCH * 128 * 128;
    float* x3 = ws + o; o += (size_t)NCH * 64 * 64;
    float* y3 = ws + o; o += (size_t)NCH * 64 * 64;
    float* x4 = ws + o; o += (size_t)NCH * 32 * 32;
    float* y4 = ws + o; o += (size_t)NCH * 32 * 32;
    float* part = ws + o;  // 8208 floats

    ssim_scale0_kernel<<<dim3(8, 16, NCH), 256, 0, stream>>>(
        x, y, kern, part, x1, y1, x2, y2, x3, y3, x4, y4);

    ssim_rest_kernel<<<dim3(1, 1, 1032), 256, 0, stream>>>(
        x1, y1, x2, y2, x3, y3, x4, y4, kern, part);

    finalize_kernel<<<1, 256, 0, stream>>>(part, wts, out);
}

// Round 14
// 57.809 us; speedup vs baseline: 1.3851x; 1.1217x over previous
//
#include <hip/hip_runtime.h>
#include <hip/hip_fp16.h>

#define NCH 24
#define KS 11
#define TH 32          // output rows per tile
#define TW 64          // output cols per tile
#define IWC 76         // LDS col stride (>= TW+10+2, mult of 4)

typedef float f32x2 __attribute__((ext_vector_type(2)));
typedef __half2 hbuf_t[TH][IWC];   // one field-PAIR: 32 x 76 half2 (9728 B)

// ===== vertical pass: packed f32x2 conv -> fp16x2 LDS, 10-deep prefetch ===
// field pairs: vb01 = (x, y), vb23 = (xx+yy, xy)
template<bool GUARD>
__device__ __forceinline__ void v_pass_pk(
    const float* __restrict__ Xp, const float* __restrict__ Yp,
    const float* __restrict__ k, int H, int W, int gx0, int gy0, int tid,
    __half2 (*vb01)[IWC], __half2 (*vb23)[IWC])
{
    if (tid < 3 * IWC) {
        const int c  = tid % IWC;
        const int rg = tid / IWC;
        const int r0 = rg * 11;              // v-rows r0..r0+10 (row 32 discarded)
        const int gc = gx0 + c;
        const bool cok = (!GUARD) || (gc < W);

        f32x2 a01[11], a23[11];
#pragma unroll
        for (int i = 0; i < 11; ++i) {
            a01[i] = (f32x2){0.f, 0.f};
            a23[i] = (f32x2){0.f, 0.f};
        }

        const float* xptr = Xp + (size_t)(gy0 + r0) * W + gc;
        const float* yptr = Yp + (size_t)(gy0 + r0) * W + gc;

        float xr[10], yr[10];
#pragma unroll
        for (int i = 0; i < 10; ++i) {
            if (GUARD) {
                const int gy = gy0 + r0 + i;
                xr[i] = 0.f; yr[i] = 0.f;
                if (cok && gy < H) { xr[i] = xptr[0]; yr[i] = yptr[0]; }
            } else {
                xr[i] = xptr[0]; yr[i] = yptr[0];
            }
            xptr += W; yptr += W;
        }

#pragma unroll
        for (int ri = 0; ri < 21; ++ri) {
            const int s = ri % 10;           // static under full unroll
            const float xv = xr[s], yv = yr[s];
            if (ri + 10 < 21) {              // prefetch row ri+10 into slot s
                if (GUARD) {
                    const int gy = gy0 + r0 + ri + 10;
                    xr[s] = 0.f; yr[s] = 0.f;
                    if (cok && gy < H) { xr[s] = xptr[0]; yr[s] = yptr[0]; }
                } else {
                    xr[s] = xptr[0]; yr[s] = yptr[0];
                }
                xptr += W; yptr += W;
            }

            f32x2 vxy, vsx;
            vxy.x = xv; vxy.y = yv;
            vsx.x = fmaf(yv, yv, xv * xv);   // xx+yy
            vsx.y = xv * yv;                 // xy
#pragma unroll
            for (int rv = 0; rv < 11; ++rv) {
                if (rv < (ri > 10 ? ri - 10 : 0)) continue;   // compile-time folded
                if (rv > (ri < 10 ? ri : 10)) continue;
                const float kt = k[ri - rv];
                f32x2 kv; kv.x = kt; kv.y = kt;
                a01[rv] += kv * vxy;         // v_pk_fma_f32
                a23[rv] += kv * vsx;
            }
        }
#pragma unroll
        for (int rv = 0; rv < 11; ++rv) {
            const int r = r0 + rv;
            if (r < TH) {
                vb01[r][c] = __floats2half2_rn(a01[rv].x, a01[rv].y);  // RNE, unbiased
                vb23[r][c] = __floats2half2_rn(a23[rv].x, a23[rv].y);
            }
        }
    }
}

// ===== horizontal pass: fp16x2 LDS -> f32x2 pk-conv + SSIM ================
// Consume-once transposed loop: each half2 unpacked once, short live range.
template<bool GUARD>
__device__ __forceinline__ void h_pass_pk(
    const float* __restrict__ k, int H, int W, int gx0, int gy0, int tid,
    const __half2 (*vb01)[IWC], const __half2 (*vb23)[IWC],
    float& ss_acc, float& cs_acc)
{
    const float c1 = 1e-4f, c2 = 9e-4f;
    const int row = tid >> 3;
    const int cg  = tid & 7;
    const int c0  = cg * 8;
    const bool rowok = (!GUARD) || ((gy0 + row) <= (H - KS));

    f32x2 h01[8], h23[8];
#pragma unroll
    for (int j = 0; j < 8; ++j) {
        h01[j] = (f32x2){0.f, 0.f};
        h23[j] = (f32x2){0.f, 0.f};
    }

#pragma unroll
    for (int fp = 0; fp < 2; ++fp) {
        const uint4* p = reinterpret_cast<const uint4*>(
            fp == 0 ? &vb01[row][c0] : &vb23[row][c0]);
        f32x2* h2 = (fp == 0) ? h01 : h23;
#pragma unroll
        for (int b = 0; b < 5; ++b) {
            uint4 q = p[b];
            unsigned qs[4] = {q.x, q.y, q.z, q.w};
#pragma unroll
            for (int u = 0; u < 4; ++u) {
                const int i = 4 * b + u;
                if (i > 18) continue;        // only w[0..18] used
                __half2 hv = *reinterpret_cast<const __half2*>(&qs[u]);
                float2 f = __half22float2(hv);
                f32x2 w; w.x = f.x; w.y = f.y;
#pragma unroll
                for (int j = 0; j < 8; ++j) {
                    const int t = i - j;     // compile-time folded
                    if (t >= 0 && t < KS) {
                        f32x2 kv; kv.x = k[t]; kv.y = k[t];
                        h2[j] += kv * w;     // v_pk_fma_f32
                    }
                }
            }
        }
    }

#pragma unroll
    for (int j = 0; j < 8; ++j) {
        bool ok = rowok && ((!GUARD) || ((gx0 + c0 + j) <= (W - KS)));
        if (ok) {
            float mx = h01[j].x, my = h01[j].y;
            float S = h23[j].x, vxy = h23[j].y;
            float mxx = mx * mx, myy = my * my, mxy = mx * my;
            float msum = mxx + myy;
            float sxy = vxy - mxy, ssum = S - msum;
            float cs = (2.f * sxy + c2) * __builtin_amdgcn_rcpf(ssum + c2);
            float ssv = (2.f * mxy + c1) * __builtin_amdgcn_rcpf(msum + c1) * cs;
            ss_acc += ssv; cs_acc += cs;
        }
    }
}

__device__ __forceinline__ void block_reduce_store(
    float ss_acc, float cs_acc, int tid, float* red, float* slot)
{
    for (int off = 32; off > 0; off >>= 1) {
        ss_acc += __shfl_down(ss_acc, off);
        cs_acc += __shfl_down(cs_acc, off);
    }
    const int wave = tid >> 6;
    if ((tid & 63) == 0) { red[wave * 2] = ss_acc; red[wave * 2 + 1] = cs_acc; }
    __syncthreads();
    if (tid == 0) {
        slot[0] = red[0] + red[2] + red[4] + red[6];
        slot[1] = red[1] + red[3] + red[5] + red[7];
    }
}

// ================= scale-0: SSIM + pooled pyramid (regs + reused LDS) =====
// LDS = 2 x 9728 (fp16x2 field pairs) + 32 = 19488 B -> 6+ blocks/CU.
// LB(256,6): VGPR cap ~85 (compiler used 68 at f32; fp16 path is leaner).
// Spill signature to watch: VGPR pegged + WRITE_SIZE >> 17 MB (R6/R8/R9).
__global__ __launch_bounds__(256, 6) void ssim_scale0_kernel(
    const float* __restrict__ X, const float* __restrict__ Y,
    const float* __restrict__ kern, float* __restrict__ part,
    float* __restrict__ X1, float* __restrict__ Y1,
    float* __restrict__ X2, float* __restrict__ Y2,
    float* __restrict__ X3, float* __restrict__ Y3,
    float* __restrict__ X4, float* __restrict__ Y4)
{
    const int H = 512, W = 512;
    const int nc  = blockIdx.z;
    const int ch  = nc % 3;
    const int gx0 = blockIdx.x * TW;
    const int gy0 = blockIdx.y * TH;
    const int tid = threadIdx.x;

    __shared__ __align__(16) __half2 vb01[TH][IWC];
    __shared__ __align__(16) __half2 vb23[TH][IWC];
    __shared__ float red[8];

    float k[KS];
#pragma unroll
    for (int t = 0; t < KS; ++t) k[t] = kern[ch * KS + t];

    const float* Xp = X + (size_t)nc * H * W;
    const float* Yp = Y + (size_t)nc * H * W;

    const bool guard = (gx0 + IWC > W) || (gy0 + TH + 11 > H);
    if (guard) v_pass_pk<true >(Xp, Yp, k, H, W, gx0, gy0, tid, vb01, vb23);
    else       v_pass_pk<false>(Xp, Yp, k, H, W, gx0, gy0, tid, vb01, vb23);

    // ---- level-1 pooling into REGISTERS + global write (pre-barrier, hot) --
    float plx[2], ply[2];
    {
        const int W2 = W >> 1;
#pragma unroll
        for (int i = 0; i < 2; ++i) {
            int p = tid + i * 256;           // 16r x 32c pooled tile
            int pr = p >> 5, pc = p & 31;
            int sr = gy0 + 2 * pr, sc = gx0 + 2 * pc;
            const float* xb = Xp + (size_t)sr * W + sc;
            const float* yb = Yp + (size_t)sr * W + sc;
            float2 xa = *reinterpret_cast<const float2*>(xb);
            float2 xc = *reinterpret_cast<const float2*>(xb + W);
            float2 ya = *reinterpret_cast<const float2*>(yb);
            float2 yc = *reinterpret_cast<const float2*>(yb + W);
            plx[i] = 0.25f * (xa.x + xa.y + xc.x + xc.y);
            ply[i] = 0.25f * (ya.x + ya.y + yc.x + yc.y);
            size_t di = (size_t)nc * W2 * W2 + (size_t)((gy0 >> 1) + pr) * W2 + ((gx0 >> 1) + pc);
            X1[di] = plx[i];
            Y1[di] = ply[i];
        }
    }
    __syncthreads();

    float ss_acc = 0.f, cs_acc = 0.f;
    if (guard) h_pass_pk<true >(k, H, W, gx0, gy0, tid, vb01, vb23, ss_acc, cs_acc);
    else       h_pass_pk<false>(k, H, W, gx0, gy0, tid, vb01, vb23, ss_acc, cs_acc);
    __syncthreads();                         // all h-pass LDS reads done

    // ---- stage lvl1 regs into reused LDS; build levels 2-4 ----------------
    float* pb = (float*)vb01;                // 2432 floats available, need 1344
    pb[tid]        = plx[0];
    pb[tid + 256]  = plx[1];
    pb[512 + tid]  = ply[0];
    pb[768 + tid]  = ply[1];
    __syncthreads();
    {
        const int W4 = W >> 2;               // level 2: 8r x 16c per array
        int a = tid >> 7, p = tid & 127;
        int pr = p >> 4, pc = p & 15;
        const float* src = pb + a * 512;
        float v = 0.25f * (src[(2*pr)*32 + 2*pc] + src[(2*pr)*32 + 2*pc + 1] +
                           src[(2*pr+1)*32 + 2*pc] + src[(2*pr+1)*32 + 2*pc + 1]);
        pb[1024 + a * 128 + p] = v;
        size_t di = (size_t)nc * W4 * W4 + (size_t)((gy0 >> 2) + pr) * W4 + ((gx0 >> 2) + pc);
        (a ? Y2 : X2)[di] = v;
    }
    __syncthreads();
    if (tid < 64) {
        const int W8 = W >> 3;               // level 3: 4r x 8c per array
        int a = tid >> 5, p = tid & 31;
        int pr = p >> 3, pc = p & 7;
        const float* src = pb + 1024 + a * 128;
        float v = 0.25f * (src[(2*pr)*16 + 2*pc] + src[(2*pr)*16 + 2*pc + 1] +
                           src[(2*pr+1)*16 + 2*pc] + src[(2*pr+1)*16 + 2*pc + 1]);
        pb[1280 + a * 32 + p] = v;
        size_t di = (size_t)nc * W8 * W8 + (size_t)((gy0 >> 3) + pr) * W8 + ((gx0 >> 3) + pc);
        (a ? Y3 : X3)[di] = v;
    }
    __syncthreads();
    if (tid < 16) {
        const int W16 = W >> 4;              // level 4: 2r x 4c per array
        int a = tid >> 3, p = tid & 7;
        int pr = p >> 2, pc = p & 3;
        const float* src = pb + 1280 + a * 32;
        float v = 0.25f * (src[(2*pr)*8 + 2*pc] + src[(2*pr)*8 + 2*pc + 1] +
                           src[(2*pr+1)*8 + 2*pc] + src[(2*pr+1)*8 + 2*pc + 1]);
        size_t di = (size_t)nc * W16 * W16 + (size_t)((gy0 >> 4) + pr) * W16 + ((gx0 >> 4) + pc);
        (a ? Y4 : X4)[di] = v;
    }

    int t = blockIdx.y * gridDim.x + blockIdx.x;
    block_reduce_store(ss_acc, cs_acc, tid, red,
                       part + ((size_t)nc * (gridDim.x * gridDim.y) + t) * 2);
}

// ================= merged scales 1-4 ======================================
__global__ __launch_bounds__(256, 6) void ssim_rest_kernel(
    const float* __restrict__ x1, const float* __restrict__ y1,
    const float* __restrict__ x2, const float* __restrict__ y2,
    const float* __restrict__ x3, const float* __restrict__ y3,
    const float* __restrict__ x4, const float* __restrict__ y4,
    const float* __restrict__ kern, float* __restrict__ part)
{
    const int z = blockIdx.z;
    const int tid = threadIdx.x;

    int img, bx, by, H, poff, nt, gw;
    const float *Xs, *Ys;
    if (z < 768)       { int r = z;        img = r >> 5; int t = r & 31; bx = t & 3; by = t >> 2; H = 256; Xs = x1; Ys = y1; poff = 6144; nt = 32; gw = 4; }
    else if (z < 960)  { int r = z - 768;  img = r >> 3; int t = r & 7;  bx = t & 1; by = t >> 1; H = 128; Xs = x2; Ys = y2; poff = 7680; nt = 8;  gw = 2; }
    else if (z < 1008) { int r = z - 960;  img = r >> 1; bx = 0; by = r & 1;         H = 64;  Xs = x3; Ys = y3; poff = 8064; nt = 2;  gw = 1; }
    else               { img = z - 1008;   bx = 0; by = 0;                           H = 32;  Xs = x4; Ys = y4; poff = 8160; nt = 1;  gw = 1; }
    const int W = H;
    const int gx0 = bx * TW, gy0 = by * TH;
    const int ch = img % 3;

    __shared__ __align__(16) __half2 vb01[TH][IWC];
    __shared__ __align__(16) __half2 vb23[TH][IWC];
    __shared__ float red[8];

    float k[KS];
#pragma unroll
    for (int t = 0; t < KS; ++t) k[t] = kern[ch * KS + t];

    const float* Xp = Xs + (size_t)img * H * W;
    const float* Yp = Ys + (size_t)img * H * W;

    const bool guard = (gx0 + IWC > W) || (gy0 + TH + 11 > H);
    if (guard) v_pass_pk<true >(Xp, Yp, k, H, W, gx0, gy0, tid, vb01, vb23);
    else       v_pass_pk<false>(Xp, Yp, k, H, W, gx0, gy0, tid, vb01, vb23);
    __syncthreads();

    float ss_acc = 0.f, cs_acc = 0.f;
    if (guard) h_pass_pk<true >(k, H, W, gx0, gy0, tid, vb01, vb23, ss_acc, cs_acc);
    else       h_pass_pk<false>(k, H, W, gx0, gy0, tid, vb01, vb23, ss_acc, cs_acc);

    int tl = by * gw + bx;
    block_reduce_store(ss_acc, cs_acc, tid, red,
                       part + poff + ((size_t)img * nt + tl) * 2);
}

// ================= finalize ==============================================
__global__ __launch_bounds__(256) void finalize_kernel(
    const float* __restrict__ part, const float* __restrict__ wts,
    float* __restrict__ out)
{
    __shared__ float smean[NCH][5];
    __shared__ float prods[NCH];
    const int ntiles[5] = {128, 32, 8, 2, 1};
    const int bases[5]  = {0, 6144, 7680, 8064, 8160};
    const float counts[5] = {252004.f, 60516.f, 13924.f, 2916.f, 484.f};
    int tid = threadIdx.x;

    for (int p = tid; p < NCH * 5; p += blockDim.x) {
        int s = p % 5, nc = p / 5;
        int nt = ntiles[s];
        const float* base = part + bases[s] + (size_t)nc * nt * 2;
        int sel = (s == 4) ? 0 : 1;   // ss for last scale, cs otherwise
        float acc = 0.f;
        for (int t = 0; t < nt; ++t) acc += base[t * 2 + sel];
        smean[nc][s] = acc / counts[s];
    }
    __syncthreads();
    if (tid < NCH) {
        float pr = 1.f;
#pragma unroll
        for (int s = 0; s < 5; ++s) {
            float v = fmaxf(smean[tid][s], 0.f);
            pr *= powf(v, wts[s]);
        }
        prods[tid] = pr;
    }
    __syncthreads();
    if (tid == 0) {
        float m = 0.f;
        for (int i = 0; i < NCH; ++i) m += prods[i];
        out[0] = m / (float)NCH;
    }
}

extern "C" void kernel_launch(void* const* d_in, const int* in_sizes, int n_in,
                              void* d_out, int out_size, void* d_ws, size_t ws_size,
                              hipStream_t stream)
{
    const float* x    = (const float*)d_in[0];
    const float* y    = (const float*)d_in[1];
    const float* kern = (const float*)d_in[2];
    const float* wts  = (const float*)d_in[3];
    float* out = (float*)d_out;
    float* ws  = (float*)d_ws;

    size_t o = 0;
    float* x1 = ws + o; o += (size_t)NCH * 256 * 256;
    float* y1 = ws + o; o += (size_t)NCH * 256 * 256;
    float* x2 = ws + o; o += (size_t)NCH * 128 * 128;
    float* y2 = ws + o; o += (size_t)NCH * 128 * 128;
    float* x3 = ws + o; o += (size_t)NCH * 64 * 64;
    float* y3 = ws + o; o += (size_t)NCH * 64 * 64;
    float* x4 = ws + o; o += (size_t)NCH * 32 * 32;
    float* y4 = ws + o; o += (size_t)NCH * 32 * 32;
    float* part = ws + o;  // 8208 floats

    ssim_scale0_kernel<<<dim3(8, 16, NCH), 256, 0, stream>>>(
        x, y, kern, part, x1, y1, x2, y2, x3, y3, x4, y4);

    ssim_rest_kernel<<<dim3(1, 1, 1032), 256, 0, stream>>>(
        x1, y1, x2, y2, x3, y3, x4, y4, kern, part);

    finalize_kernel<<<1, 256, 0, stream>>>(part, wts, out);
}

// Round 15
// 56.277 us; speedup vs baseline: 1.4228x; 1.0272x over previous
//
#include <hip/hip_runtime.h>
#include <hip/hip_fp16.h>

#define NCH 24
#define KS 11
#define TH 32          // output rows per tile
#define TW 64          // output cols per tile
#define IWC 76         // LDS col stride (>= TW+10+2, mult of 4)

typedef float f32x2 __attribute__((ext_vector_type(2)));

// ===== conv inner: accumulate packed pairs ================================
__device__ __forceinline__ void conv_acc(
    f32x2* a01, f32x2* a23, const float* k, int ri, float xv, float yv)
{
    f32x2 vxy, vsx;
    vxy.x = xv; vxy.y = yv;
    vsx.x = fmaf(yv, yv, xv * xv);   // xx+yy
    vsx.y = xv * yv;                 // xy
#pragma unroll
    for (int rv = 0; rv < 11; ++rv) {
        if (rv < (ri > 10 ? ri - 10 : 0)) continue;   // compile-time folded
        if (rv > (ri < 10 ? ri : 10)) continue;
        const float kt = k[ri - rv];
        f32x2 kv; kv.x = kt; kv.y = kt;
        a01[rv] += kv * vxy;         // v_pk_fma_f32
        a23[rv] += kv * vsx;
    }
}

__device__ __forceinline__ void v_store(
    __half2 (*vb01)[IWC], __half2 (*vb23)[IWC], int r0, int c,
    const f32x2* a01, const f32x2* a23)
{
#pragma unroll
    for (int rv = 0; rv < 11; ++rv) {
        const int r = r0 + rv;
        if (r < TH) {
            vb01[r][c] = __floats2half2_rn(a01[rv].x, a01[rv].y);  // RNE
            vb23[r][c] = __floats2half2_rn(a23[rv].x, a23[rv].y);
        }
    }
}

// ===== scale-0 vertical pass: f32 inputs, 10-deep rotating prefetch =======
template<bool GUARD>
__device__ __forceinline__ void v_pass_f32(
    const float* __restrict__ Xp, const float* __restrict__ Yp,
    const float* __restrict__ k, int H, int W, int gx0, int gy0, int tid,
    __half2 (*vb01)[IWC], __half2 (*vb23)[IWC])
{
    if (tid < 3 * IWC) {
        const int c  = tid % IWC;
        const int rg = tid / IWC;
        const int r0 = rg * 11;
        const int gc = gx0 + c;
        const bool cok = (!GUARD) || (gc < W);

        f32x2 a01[11], a23[11];
#pragma unroll
        for (int i = 0; i < 11; ++i) { a01[i] = (f32x2){0.f,0.f}; a23[i] = (f32x2){0.f,0.f}; }

        const float* xptr = Xp + (size_t)(gy0 + r0) * W + gc;
        const float* yptr = Yp + (size_t)(gy0 + r0) * W + gc;

        float xr[10], yr[10];
#pragma unroll
        for (int i = 0; i < 10; ++i) {
            if (GUARD) {
                const int gy = gy0 + r0 + i;
                xr[i] = 0.f; yr[i] = 0.f;
                if (cok && gy < H) { xr[i] = xptr[0]; yr[i] = yptr[0]; }
            } else {
                xr[i] = xptr[0]; yr[i] = yptr[0];
            }
            xptr += W; yptr += W;
        }

#pragma unroll
        for (int ri = 0; ri < 21; ++ri) {
            const int s = ri % 10;
            const float xv = xr[s], yv = yr[s];
            if (ri + 10 < 21) {
                if (GUARD) {
                    const int gy = gy0 + r0 + ri + 10;
                    xr[s] = 0.f; yr[s] = 0.f;
                    if (cok && gy < H) { xr[s] = xptr[0]; yr[s] = yptr[0]; }
                } else {
                    xr[s] = xptr[0]; yr[s] = yptr[0];
                }
                xptr += W; yptr += W;
            }
            conv_acc(a01, a23, k, ri, xv, yv);
        }
        v_store(vb01, vb23, r0, c, a01, a23);
    }
}

// ===== rest vertical pass: interleaved half2 input (one 4B load/row) ======
template<bool GUARD>
__device__ __forceinline__ void v_pass_h2(
    const __half2* __restrict__ XYp,
    const float* __restrict__ k, int H, int W, int gx0, int gy0, int tid,
    __half2 (*vb01)[IWC], __half2 (*vb23)[IWC])
{
    if (tid < 3 * IWC) {
        const int c  = tid % IWC;
        const int rg = tid / IWC;
        const int r0 = rg * 11;
        const int gc = gx0 + c;
        const bool cok = (!GUARD) || (gc < W);

        f32x2 a01[11], a23[11];
#pragma unroll
        for (int i = 0; i < 11; ++i) { a01[i] = (f32x2){0.f,0.f}; a23[i] = (f32x2){0.f,0.f}; }

        const __half2* p = XYp + (size_t)(gy0 + r0) * W + gc;

        __half2 hr[10];
#pragma unroll
        for (int i = 0; i < 10; ++i) {
            if (GUARD) {
                const int gy = gy0 + r0 + i;
                hr[i] = __floats2half2_rn(0.f, 0.f);
                if (cok && gy < H) hr[i] = p[0];
            } else {
                hr[i] = p[0];
            }
            p += W;
        }

#pragma unroll
        for (int ri = 0; ri < 21; ++ri) {
            const int s = ri % 10;
            float2 f = __half22float2(hr[s]);
            if (ri + 10 < 21) {
                if (GUARD) {
                    const int gy = gy0 + r0 + ri + 10;
                    hr[s] = __floats2half2_rn(0.f, 0.f);
                    if (cok && gy < H) hr[s] = p[0];
                } else {
                    hr[s] = p[0];
                }
                p += W;
            }
            conv_acc(a01, a23, k, ri, f.x, f.y);
        }
        v_store(vb01, vb23, r0, c, a01, a23);
    }
}

// ===== horizontal pass: fp16x2 LDS -> f32x2 pk-conv + SSIM ================
template<bool GUARD>
__device__ __forceinline__ void h_pass_pk(
    const float* __restrict__ k, int H, int W, int gx0, int gy0, int tid,
    const __half2 (*vb01)[IWC], const __half2 (*vb23)[IWC],
    float& ss_acc, float& cs_acc)
{
    const float c1 = 1e-4f, c2 = 9e-4f;
    const int row = tid >> 3;
    const int cg  = tid & 7;
    const int c0  = cg * 8;
    const bool rowok = (!GUARD) || ((gy0 + row) <= (H - KS));

    f32x2 h01[8], h23[8];
#pragma unroll
    for (int j = 0; j < 8; ++j) { h01[j] = (f32x2){0.f,0.f}; h23[j] = (f32x2){0.f,0.f}; }

#pragma unroll
    for (int fp = 0; fp < 2; ++fp) {
        const uint4* p = reinterpret_cast<const uint4*>(
            fp == 0 ? &vb01[row][c0] : &vb23[row][c0]);
        f32x2* h2 = (fp == 0) ? h01 : h23;
#pragma unroll
        for (int b = 0; b < 5; ++b) {
            uint4 q = p[b];
            unsigned qs[4] = {q.x, q.y, q.z, q.w};
#pragma unroll
            for (int u = 0; u < 4; ++u) {
                const int i = 4 * b + u;
                if (i > 17) continue;        // w[0..17] used (j<=7, t<=10)
                __half2 hv = *reinterpret_cast<const __half2*>(&qs[u]);
                float2 f = __half22float2(hv);
                f32x2 w; w.x = f.x; w.y = f.y;
#pragma unroll
                for (int j = 0; j < 8; ++j) {
                    const int t = i - j;
                    if (t >= 0 && t < KS) {
                        f32x2 kv; kv.x = k[t]; kv.y = k[t];
                        h2[j] += kv * w;     // v_pk_fma_f32
                    }
                }
            }
        }
    }

#pragma unroll
    for (int j = 0; j < 8; ++j) {
        bool ok = rowok && ((!GUARD) || ((gx0 + c0 + j) <= (W - KS)));
        if (ok) {
            float mx = h01[j].x, my = h01[j].y;
            float S = h23[j].x, vxy = h23[j].y;
            float mxx = mx * mx, myy = my * my, mxy = mx * my;
            float msum = mxx + myy;
            float sxy = vxy - mxy, ssum = S - msum;
            float cs = (2.f * sxy + c2) * __builtin_amdgcn_rcpf(ssum + c2);
            float ssv = (2.f * mxy + c1) * __builtin_amdgcn_rcpf(msum + c1) * cs;
            ss_acc += ssv; cs_acc += cs;
        }
    }
}

__device__ __forceinline__ void block_reduce_store(
    float ss_acc, float cs_acc, int tid, float* red, float* slot)
{
    for (int off = 32; off > 0; off >>= 1) {
        ss_acc += __shfl_down(ss_acc, off);
        cs_acc += __shfl_down(cs_acc, off);
    }
    const int wave = tid >> 6;
    if ((tid & 63) == 0) { red[wave * 2] = ss_acc; red[wave * 2 + 1] = cs_acc; }
    __syncthreads();
    if (tid == 0) {
        slot[0] = red[0] + red[2] + red[4] + red[6];
        slot[1] = red[1] + red[3] + red[5] + red[7];
    }
}

// ================= scale-0: SSIM + interleaved-half2 pooled pyramid =======
// LDS = vb 19456 + pl1 4096 + pl2 1024 + pl3 256 + red 32 ~= 24.9 KB -> 6/CU.
// Pyramid stored as (x,y) half2: halves pyramid write AND rest-kernel read
// bytes+instructions. Pooling pooled in f32 (LDS float2), quantized once per
// level (no compounding). LB(256,6) -> VGPR cap 85 (R14 passed clean).
__global__ __launch_bounds__(256, 6) void ssim_scale0_kernel(
    const float* __restrict__ X, const float* __restrict__ Y,
    const float* __restrict__ kern, float* __restrict__ part,
    __half2* __restrict__ XY1, __half2* __restrict__ XY2,
    __half2* __restrict__ XY3, __half2* __restrict__ XY4)
{
    const int H = 512, W = 512;
    const int nc  = blockIdx.z;
    const int ch  = nc % 3;
    const int gx0 = blockIdx.x * TW;
    const int gy0 = blockIdx.y * TH;
    const int tid = threadIdx.x;

    __shared__ __align__(16) __half2 vb01[TH][IWC];
    __shared__ __align__(16) __half2 vb23[TH][IWC];
    __shared__ float2 pl1[512];   // f32 lvl1 staging (16r x 32c)
    __shared__ float2 pl2[128];   // lvl2 (8r x 16c)
    __shared__ float2 pl3[32];    // lvl3 (4r x 8c)
    __shared__ float red[8];

    float k[KS];
#pragma unroll
    for (int t = 0; t < KS; ++t) k[t] = kern[ch * KS + t];

    const float* Xp = X + (size_t)nc * H * W;
    const float* Yp = Y + (size_t)nc * H * W;

    const bool guard = (gx0 + IWC > W) || (gy0 + TH + 11 > H);
    if (guard) v_pass_f32<true >(Xp, Yp, k, H, W, gx0, gy0, tid, vb01, vb23);
    else       v_pass_f32<false>(Xp, Yp, k, H, W, gx0, gy0, tid, vb01, vb23);

    // ---- lvl1 pooling (pre-barrier, lines L2-hot): regs -> global + LDS ----
    {
        const int W2 = W >> 1;
#pragma unroll
        for (int i = 0; i < 2; ++i) {
            int p = tid + i * 256;           // 16r x 32c pooled tile
            int pr = p >> 5, pc = p & 31;
            int sr = gy0 + 2 * pr, sc = gx0 + 2 * pc;
            const float* xb = Xp + (size_t)sr * W + sc;
            const float* yb = Yp + (size_t)sr * W + sc;
            float2 xa = *reinterpret_cast<const float2*>(xb);
            float2 xc = *reinterpret_cast<const float2*>(xb + W);
            float2 ya = *reinterpret_cast<const float2*>(yb);
            float2 yc = *reinterpret_cast<const float2*>(yb + W);
            float px = 0.25f * (xa.x + xa.y + xc.x + xc.y);
            float py = 0.25f * (ya.x + ya.y + yc.x + yc.y);
            pl1[p] = make_float2(px, py);
            size_t di = (size_t)nc * W2 * W2 + (size_t)((gy0 >> 1) + pr) * W2 + ((gx0 >> 1) + pc);
            XY1[di] = __floats2half2_rn(px, py);
        }
    }
    __syncthreads();   // covers vb + pl1

    float ss_acc = 0.f, cs_acc = 0.f;
    if (guard) h_pass_pk<true >(k, H, W, gx0, gy0, tid, vb01, vb23, ss_acc, cs_acc);
    else       h_pass_pk<false>(k, H, W, gx0, gy0, tid, vb01, vb23, ss_acc, cs_acc);

    // ---- lvl2 from pl1 (no barrier needed: pl1 pre-main-barrier) ----------
    if (tid < 128) {
        const int W4 = W >> 2;               // 8r x 16c
        int pr = tid >> 4, pc = tid & 15;
        float2 a = pl1[(2*pr)*32 + 2*pc],     b = pl1[(2*pr)*32 + 2*pc + 1];
        float2 cfl = pl1[(2*pr+1)*32 + 2*pc], d = pl1[(2*pr+1)*32 + 2*pc + 1];
        float vx = 0.25f * (a.x + b.x + cfl.x + d.x);
        float vy = 0.25f * (a.y + b.y + cfl.y + d.y);
        pl2[tid] = make_float2(vx, vy);
        size_t di = (size_t)nc * W4 * W4 + (size_t)((gy0 >> 2) + pr) * W4 + ((gx0 >> 2) + pc);
        XY2[di] = __floats2half2_rn(vx, vy);
    }
    __syncthreads();
    if (tid < 32) {
        const int W8 = W >> 3;               // 4r x 8c
        int pr = tid >> 3, pc = tid & 7;
        float2 a = pl2[(2*pr)*16 + 2*pc],     b = pl2[(2*pr)*16 + 2*pc + 1];
        float2 cfl = pl2[(2*pr+1)*16 + 2*pc], d = pl2[(2*pr+1)*16 + 2*pc + 1];
        float vx = 0.25f * (a.x + b.x + cfl.x + d.x);
        float vy = 0.25f * (a.y + b.y + cfl.y + d.y);
        pl3[tid] = make_float2(vx, vy);
        size_t di = (size_t)nc * W8 * W8 + (size_t)((gy0 >> 3) + pr) * W8 + ((gx0 >> 3) + pc);
        XY3[di] = __floats2half2_rn(vx, vy);
    }
    __syncthreads();
    if (tid < 8) {
        const int W16 = W >> 4;              // 2r x 4c
        int pr = tid >> 2, pc = tid & 3;
        float2 a = pl3[(2*pr)*8 + 2*pc],     b = pl3[(2*pr)*8 + 2*pc + 1];
        float2 cfl = pl3[(2*pr+1)*8 + 2*pc], d = pl3[(2*pr+1)*8 + 2*pc + 1];
        float vx = 0.25f * (a.x + b.x + cfl.x + d.x);
        float vy = 0.25f * (a.y + b.y + cfl.y + d.y);
        size_t di = (size_t)nc * W16 * W16 + (size_t)((gy0 >> 4) + pr) * W16 + ((gx0 >> 4) + pc);
        XY4[di] = __floats2half2_rn(vx, vy);
    }

    int t = blockIdx.y * gridDim.x + blockIdx.x;
    block_reduce_store(ss_acc, cs_acc, tid, red,
                       part + ((size_t)nc * (gridDim.x * gridDim.y) + t) * 2);
}

// ================= merged scales 1-4 (interleaved half2 inputs) ===========
__global__ __launch_bounds__(256, 6) void ssim_rest_kernel(
    const __half2* __restrict__ xy1, const __half2* __restrict__ xy2,
    const __half2* __restrict__ xy3, const __half2* __restrict__ xy4,
    const float* __restrict__ kern, float* __restrict__ part)
{
    const int z = blockIdx.z;
    const int tid = threadIdx.x;

    int img, bx, by, H, poff, nt, gw;
    const __half2* XYs;
    if (z < 768)       { int r = z;        img = r >> 5; int t = r & 31; bx = t & 3; by = t >> 2; H = 256; XYs = xy1; poff = 6144; nt = 32; gw = 4; }
    else if (z < 960)  { int r = z - 768;  img = r >> 3; int t = r & 7;  bx = t & 1; by = t >> 1; H = 128; XYs = xy2; poff = 7680; nt = 8;  gw = 2; }
    else if (z < 1008) { int r = z - 960;  img = r >> 1; bx = 0; by = r & 1;         H = 64;  XYs = xy3; poff = 8064; nt = 2;  gw = 1; }
    else               { img = z - 1008;   bx = 0; by = 0;                           H = 32;  XYs = xy4; poff = 8160; nt = 1;  gw = 1; }
    const int W = H;
    const int gx0 = bx * TW, gy0 = by * TH;
    const int ch = img % 3;

    __shared__ __align__(16) __half2 vb01[TH][IWC];
    __shared__ __align__(16) __half2 vb23[TH][IWC];
    __shared__ float red[8];

    float k[KS];
#pragma unroll
    for (int t = 0; t < KS; ++t) k[t] = kern[ch * KS + t];

    const __half2* XYp = XYs + (size_t)img * H * W;

    const bool guard = (gx0 + IWC > W) || (gy0 + TH + 11 > H);
    if (guard) v_pass_h2<true >(XYp, k, H, W, gx0, gy0, tid, vb01, vb23);
    else       v_pass_h2<false>(XYp, k, H, W, gx0, gy0, tid, vb01, vb23);
    __syncthreads();

    float ss_acc = 0.f, cs_acc = 0.f;
    if (guard) h_pass_pk<true >(k, H, W, gx0, gy0, tid, vb01, vb23, ss_acc, cs_acc);
    else       h_pass_pk<false>(k, H, W, gx0, gy0, tid, vb01, vb23, ss_acc, cs_acc);

    int tl = by * gw + bx;
    block_reduce_store(ss_acc, cs_acc, tid, red,
                       part + poff + ((size_t)img * nt + tl) * 2);
}

// ================= finalize ==============================================
__global__ __launch_bounds__(256) void finalize_kernel(
    const float* __restrict__ part, const float* __restrict__ wts,
    float* __restrict__ out)
{
    __shared__ float smean[NCH][5];
    __shared__ float prods[NCH];
    const int ntiles[5] = {128, 32, 8, 2, 1};
    const int bases[5]  = {0, 6144, 7680, 8064, 8160};
    const float counts[5] = {252004.f, 60516.f, 13924.f, 2916.f, 484.f};
    int tid = threadIdx.x;

    for (int p = tid; p < NCH * 5; p += blockDim.x) {
        int s = p % 5, nc = p / 5;
        int nt = ntiles[s];
        const float* base = part + bases[s] + (size_t)nc * nt * 2;
        int sel = (s == 4) ? 0 : 1;   // ss for last scale, cs otherwise
        float acc = 0.f;
        for (int t = 0; t < nt; ++t) acc += base[t * 2 + sel];
        smean[nc][s] = acc / counts[s];
    }
    __syncthreads();
    if (tid < NCH) {
        float pr = 1.f;
#pragma unroll
        for (int s = 0; s < 5; ++s) {
            float v = fmaxf(smean[tid][s], 0.f);
            pr *= powf(v, wts[s]);
        }
        prods[tid] = pr;
    }
    __syncthreads();
    if (tid == 0) {
        float m = 0.f;
        for (int i = 0; i < NCH; ++i) m += prods[i];
        out[0] = m / (float)NCH;
    }
}

extern "C" void kernel_launch(void* const* d_in, const int* in_sizes, int n_in,
                              void* d_out, int out_size, void* d_ws, size_t ws_size,
                              hipStream_t stream)
{
    const float* x    = (const float*)d_in[0];
    const float* y    = (const float*)d_in[1];
    const float* kern = (const float*)d_in[2];
    const float* wts  = (const float*)d_in[3];
    float* out = (float*)d_out;
    float* ws  = (float*)d_ws;

    // workspace layout (float units; half2 = 1 float slot per pixel)
    size_t o = 0;
    __half2* xy1 = (__half2*)(ws + o); o += (size_t)NCH * 256 * 256;
    __half2* xy2 = (__half2*)(ws + o); o += (size_t)NCH * 128 * 128;
    __half2* xy3 = (__half2*)(ws + o); o += (size_t)NCH * 64 * 64;
    __half2* xy4 = (__half2*)(ws + o); o += (size_t)NCH * 32 * 32;
    float* part = ws + o;  // 8208 floats

    ssim_scale0_kernel<<<dim3(8, 16, NCH), 256, 0, stream>>>(
        x, y, kern, part, xy1, xy2, xy3, xy4);

    ssim_rest_kernel<<<dim3(1, 1, 1032), 256, 0, stream>>>(
        xy1, xy2, xy3, xy4, kern, part);

    finalize_kernel<<<1, 256, 0, stream>>>(part, wts, out);
}